// Round 1
// baseline (1127.050 us; speedup 1.0000x reference)
//
#include <hip/hip_runtime.h>
#include <math.h>

#define N_USERS 50000
#define N_ITEMS 50000
#define N_NODES 100000
#define EMB 64
#define N_LAYERS 3
#define N_EDGES 1600000
#define BATCH 16384
#define REG_C 1e-05f
#define SLOPE 0.01f
#define EPS_C 1e-12f

#define SCAN_CHUNK 256
#define NCHUNK ((N_NODES + SCAN_CHUNK - 1) / SCAN_CHUNK)   // 391

// ---------------- ego init: concat(u_emb, i_emb) ----------------
__global__ void k_init_ego(const float* __restrict__ u_emb,
                           const float* __restrict__ i_emb,
                           float* __restrict__ ego) {
    int idx = blockIdx.x * blockDim.x + threadIdx.x;   // float4 index
    const int n4 = N_NODES * EMB / 4;
    if (idx < n4) {
        const int u4 = N_USERS * EMB / 4;
        float4 v = (idx < u4) ? ((const float4*)u_emb)[idx]
                              : ((const float4*)i_emb)[idx - u4];
        ((float4*)ego)[idx] = v;
    }
}

// ---------------- CSR build ----------------
__global__ void k_histo(const int* __restrict__ rows, int* __restrict__ counts) {
    int e = blockIdx.x * blockDim.x + threadIdx.x;
    if (e < N_EDGES) atomicAdd(&counts[rows[e]], 1);
}

__global__ void k_chunk_sum(const int* __restrict__ counts, int* __restrict__ partials) {
    __shared__ int s[SCAN_CHUNK];
    int i = blockIdx.x * SCAN_CHUNK + threadIdx.x;
    int v = (i < N_NODES) ? counts[i] : 0;
    s[threadIdx.x] = v;
    __syncthreads();
    for (int st = SCAN_CHUNK / 2; st > 0; st >>= 1) {
        if ((int)threadIdx.x < st) s[threadIdx.x] += s[threadIdx.x + st];
        __syncthreads();
    }
    if (threadIdx.x == 0) partials[blockIdx.x] = s[0];
}

__global__ void k_scan_partials(int* __restrict__ partials) {
    __shared__ int s[512];
    int t = threadIdx.x;
    int v = (t < NCHUNK) ? partials[t] : 0;
    s[t] = v;
    __syncthreads();
    for (int st = 1; st < 512; st <<= 1) {
        int add = (t >= st) ? s[t - st] : 0;
        __syncthreads();
        s[t] += add;
        __syncthreads();
    }
    if (t < NCHUNK) partials[t] = s[t] - v;   // exclusive
}

__global__ void k_chunk_scan(const int* __restrict__ counts,
                             const int* __restrict__ partials,
                             int* __restrict__ offsets,
                             int* __restrict__ cursor) {
    __shared__ int s[SCAN_CHUNK];
    int t = threadIdx.x;
    int i = blockIdx.x * SCAN_CHUNK + t;
    int v = (i < N_NODES) ? counts[i] : 0;
    s[t] = v;
    __syncthreads();
    for (int st = 1; st < SCAN_CHUNK; st <<= 1) {
        int add = (t >= st) ? s[t - st] : 0;
        __syncthreads();
        s[t] += add;
        __syncthreads();
    }
    int excl = s[t] - v + partials[blockIdx.x];
    if (i < N_NODES) { offsets[i] = excl; cursor[i] = excl; }
    if (blockIdx.x == 0 && t == 0) offsets[N_NODES] = N_EDGES;
}

__global__ void k_scatter(const int* __restrict__ rows, const int* __restrict__ cols,
                          const float* __restrict__ vals,
                          int* __restrict__ cursor,
                          int* __restrict__ edge_col, float* __restrict__ edge_val) {
    int e = blockIdx.x * blockDim.x + threadIdx.x;
    if (e < N_EDGES) {
        int r = rows[e];
        int pos = atomicAdd(&cursor[r], 1);
        edge_col[pos] = cols[e];
        edge_val[pos] = vals[e];
    }
}

// ---------------- per-layer: gather-based segment sum ----------------
__global__ __launch_bounds__(256) void k_edge_agg(const int* __restrict__ offsets,
                                                  const int* __restrict__ edge_col,
                                                  const float* __restrict__ edge_val,
                                                  const float* __restrict__ ego,
                                                  float* __restrict__ wsacc) {
    int wid = (blockIdx.x * blockDim.x + threadIdx.x) >> 6;
    int lane = threadIdx.x & 63;
    if (wid >= N_NODES) return;
    int s0 = offsets[wid], e0 = offsets[wid + 1];
    float acc = 0.f;
    for (int k = s0; k < e0; ++k) {
        int c = edge_col[k];
        float v = edge_val[k];
        acc += v * ego[c * EMB + lane];
    }
    wsacc[wid * EMB + lane] = acc;
}

// ---------------- per-layer: t = ws@W1^T + b1 + (ego*ws)@W2^T + b2 ; leaky ----------------
__global__ __launch_bounds__(256) void k_transform(const float* __restrict__ wsacc,
                                                   float* __restrict__ ego,
                                                   const float* __restrict__ W1,
                                                   const float* __restrict__ b1,
                                                   const float* __restrict__ W2,
                                                   const float* __restrict__ b2) {
    __shared__ float w1t[64 * 65];
    __shared__ float w2t[64 * 65];
    for (int idx = threadIdx.x; idx < 4096; idx += 256) {
        int m = idx >> 6, k = idx & 63;
        w1t[k * 65 + m] = W1[idx];
        w2t[k * 65 + m] = W2[idx];
    }
    __syncthreads();
    int lane = threadIdx.x & 63;
    int wid = (blockIdx.x * blockDim.x + threadIdx.x) >> 6;
    int nw = (gridDim.x * blockDim.x) >> 6;
    float bias = b1[lane] + b2[lane];
    for (int row = wid; row < N_NODES; row += nw) {
        float wsv  = wsacc[row * EMB + lane];
        float egov = ego[row * EMB + lane];
        float affv = wsv * egov;
        float t = bias;
        #pragma unroll
        for (int k = 0; k < 64; ++k) {
            float wk = __shfl(wsv, k, 64);
            float ak = __shfl(affv, k, 64);
            t += w1t[k * 65 + lane] * wk + w2t[k * 65 + lane] * ak;
        }
        float e = (t >= 0.f) ? t : SLOPE * t;
        ego[row * EMB + lane] = e;
    }
}

// ---------------- per-layer: batch gather + partial-loss accumulation ----------------
// acc layout: [0]=dot_up, [1]=dot_un, [2]=ssq_u, [3]=ssq_p, [4]=ssq_n ; each [BATCH]
__global__ __launch_bounds__(256) void k_batch_acc(const float* __restrict__ src,
                                                   const int* __restrict__ u,
                                                   const int* __restrict__ ii,
                                                   const int* __restrict__ jj,
                                                   float* __restrict__ acc,
                                                   int normalize) {
    int wid = (blockIdx.x * blockDim.x + threadIdx.x) >> 6;
    int lane = threadIdx.x & 63;
    if (wid >= BATCH) return;
    int nu = u[wid];
    int np_ = N_USERS + ii[wid];
    int nn = N_USERS + jj[wid];
    float eu = src[nu * EMB + lane];
    float ep = src[np_ * EMB + lane];
    float en = src[nn * EMB + lane];
    float d_up = eu * ep, d_un = eu * en;
    float s_u = eu * eu, s_p = ep * ep, s_n = en * en;
    #pragma unroll
    for (int m = 32; m > 0; m >>= 1) {
        d_up += __shfl_xor(d_up, m, 64);
        d_un += __shfl_xor(d_un, m, 64);
        s_u  += __shfl_xor(s_u,  m, 64);
        s_p  += __shfl_xor(s_p,  m, 64);
        s_n  += __shfl_xor(s_n,  m, 64);
    }
    if (lane == 0) {
        if (normalize) {
            float inu = 1.f / fmaxf(sqrtf(s_u), EPS_C);
            float inp = 1.f / fmaxf(sqrtf(s_p), EPS_C);
            float inn = 1.f / fmaxf(sqrtf(s_n), EPS_C);
            d_up *= inu * inp;
            d_un *= inu * inn;
            s_u *= inu * inu;
            s_p *= inp * inp;
            s_n *= inn * inn;
        }
        acc[0 * BATCH + wid] += d_up;
        acc[1 * BATCH + wid] += d_un;
        acc[2 * BATCH + wid] += s_u;
        acc[3 * BATCH + wid] += s_p;
        acc[4 * BATCH + wid] += s_n;
    }
}

// ---------------- final scalar ----------------
__global__ __launch_bounds__(1024) void k_finalize(const float* __restrict__ acc,
                                                   float* __restrict__ out) {
    __shared__ float s1[1024], s2[1024];
    float ls = 0.f, l2 = 0.f;
    for (int b = threadIdx.x; b < BATCH; b += 1024) {
        float x = acc[0 * BATCH + b] - acc[1 * BATCH + b];
        ls += fminf(x, 0.f) - log1pf(expf(-fabsf(x)));
        l2 += acc[2 * BATCH + b] + acc[3 * BATCH + b] + acc[4 * BATCH + b];
    }
    s1[threadIdx.x] = ls; s2[threadIdx.x] = l2;
    __syncthreads();
    for (int st = 512; st > 0; st >>= 1) {
        if ((int)threadIdx.x < st) {
            s1[threadIdx.x] += s1[threadIdx.x + st];
            s2[threadIdx.x] += s2[threadIdx.x + st];
        }
        __syncthreads();
    }
    if (threadIdx.x == 0)
        out[0] = -s1[0] / (float)BATCH + REG_C * (s2[0] * 0.5f) / (float)BATCH;
}

extern "C" void kernel_launch(void* const* d_in, const int* in_sizes, int n_in,
                              void* d_out, int out_size, void* d_ws, size_t ws_size,
                              hipStream_t stream) {
    (void)in_sizes; (void)n_in; (void)out_size; (void)ws_size;
    const int*   u     = (const int*)d_in[0];
    const int*   ii    = (const int*)d_in[1];
    const int*   jj    = (const int*)d_in[2];
    const int*   rows  = (const int*)d_in[3];
    const int*   cols  = (const int*)d_in[4];
    const float* vals  = (const float*)d_in[5];
    const float* u_emb = (const float*)d_in[6];
    const float* i_emb = (const float*)d_in[7];
    const float* W1_w  = (const float*)d_in[8];
    const float* W1_b  = (const float*)d_in[9];
    const float* W2_w  = (const float*)d_in[10];
    const float* W2_b  = (const float*)d_in[11];
    float* out = (float*)d_out;

    // workspace carve-up
    char* p = (char*)d_ws;
    float* ego      = (float*)p;                    p += (size_t)N_NODES * EMB * 4;
    float* wsacc    = (float*)p;                    p += (size_t)N_NODES * EMB * 4;
    int*   edge_col = (int*)p;                      p += (size_t)N_EDGES * 4;
    float* edge_val = (float*)p;                    p += (size_t)N_EDGES * 4;
    int*   counts   = (int*)p;                      p += (size_t)N_NODES * 4;
    int*   offsets  = (int*)p;                      p += (size_t)(N_NODES + 1) * 4;
    int*   cursor   = (int*)p;                      p += (size_t)N_NODES * 4;
    int*   partials = (int*)p;                      p += 512 * 4;
    float* acc      = (float*)p;                    p += (size_t)5 * BATCH * 4;

    hipMemsetAsync(counts, 0, (size_t)N_NODES * 4, stream);
    hipMemsetAsync(acc, 0, (size_t)5 * BATCH * 4, stream);

    k_init_ego<<<(N_NODES * EMB / 4 + 255) / 256, 256, 0, stream>>>(u_emb, i_emb, ego);
    k_histo<<<(N_EDGES + 255) / 256, 256, 0, stream>>>(rows, counts);
    k_chunk_sum<<<NCHUNK, SCAN_CHUNK, 0, stream>>>(counts, partials);
    k_scan_partials<<<1, 512, 0, stream>>>(partials);
    k_chunk_scan<<<NCHUNK, SCAN_CHUNK, 0, stream>>>(counts, partials, offsets, cursor);
    k_scatter<<<(N_EDGES + 255) / 256, 256, 0, stream>>>(rows, cols, vals, cursor, edge_col, edge_val);

    // layer 0 contribution (raw ego, no normalization)
    k_batch_acc<<<BATCH * 64 / 256, 256, 0, stream>>>(ego, u, ii, jj, acc, 0);

    for (int k = 0; k < N_LAYERS; ++k) {
        k_edge_agg<<<N_NODES * 64 / 256, 256, 0, stream>>>(offsets, edge_col, edge_val, ego, wsacc);
        k_transform<<<1024, 256, 0, stream>>>(wsacc, ego,
                                              W1_w + k * 4096, W1_b + k * 64,
                                              W2_w + k * 4096, W2_b + k * 64);
        k_batch_acc<<<BATCH * 64 / 256, 256, 0, stream>>>(ego, u, ii, jj, acc, 1);
    }
    k_finalize<<<1, 1024, 0, stream>>>(acc, out);
}